// Round 1
// baseline (20045.302 us; speedup 1.0000x reference)
//
#include <hip/hip_runtime.h>
#include <math.h>

#define EPS 1e-8f

// Problem constants (fixed by reference file)
constexpr int N_USERS = 6000;
constexpr int N_ITEMS = 4000;

// ---------------------------------------------------------------------------
// GEMM: C[M,N] = op(A) @ op(B), fp32, 64x64 tile, BK=16, 256 threads, 4x4/thread
// TA=0: A is M x K row-major.  TA=1: A is K x M row-major (logical A^T).
// TB=0: B is K x N row-major.  TB=1: B is N x K row-major (logical B^T).
// ---------------------------------------------------------------------------
template <int TA, int TB>
__global__ __launch_bounds__(256) void gemm_kernel(
    const float* __restrict__ A, const float* __restrict__ B,
    float* __restrict__ C, int M, int N, int K) {
  constexpr int BM = 64, BN = 64, BK = 16;
  __shared__ float As[BK][BM + 4];
  __shared__ float Bs[BK][BN + 4];

  const int tid = threadIdx.x;
  const int ty = tid >> 4;   // 0..15
  const int tx = tid & 15;   // 0..15
  const int row0 = blockIdx.y * BM;
  const int col0 = blockIdx.x * BN;

  float acc[4][4] = {};

  for (int k0 = 0; k0 < K; k0 += BK) {
#pragma unroll
    for (int l = 0; l < 4; l++) {
      const int e = tid + l * 256;
      // ---- A tile -> As[k][m]
      if (TA == 0) {
        const int m = e >> 4, k = e & 15;
        const int gm = row0 + m, gk = k0 + k;
        As[k][m] = (gm < M && gk < K) ? A[(long)gm * K + gk] : 0.f;
      } else {
        const int k = e >> 6, m = e & 63;
        const int gm = row0 + m, gk = k0 + k;
        As[k][m] = (gm < M && gk < K) ? A[(long)gk * M + gm] : 0.f;
      }
      // ---- B tile -> Bs[k][n]
      if (TB == 0) {
        const int k = e >> 6, n = e & 63;
        const int gn = col0 + n, gk = k0 + k;
        Bs[k][n] = (gn < N && gk < K) ? B[(long)gk * N + gn] : 0.f;
      } else {
        const int n = e >> 4, k = e & 15;
        const int gn = col0 + n, gk = k0 + k;
        Bs[k][n] = (gn < N && gk < K) ? B[(long)gn * K + gk] : 0.f;
      }
    }
    __syncthreads();

#pragma unroll
    for (int k = 0; k < BK; k++) {
      const float4 av = *(const float4*)&As[k][ty * 4];
      const float4 bv = *(const float4*)&Bs[k][tx * 4];
      const float a[4] = {av.x, av.y, av.z, av.w};
      const float b[4] = {bv.x, bv.y, bv.z, bv.w};
#pragma unroll
      for (int i = 0; i < 4; i++)
#pragma unroll
        for (int j = 0; j < 4; j++) acc[i][j] = fmaf(a[i], b[j], acc[i][j]);
    }
    __syncthreads();
  }

#pragma unroll
  for (int i = 0; i < 4; i++) {
    const int gm = row0 + ty * 4 + i;
    if (gm >= M) continue;
#pragma unroll
    for (int j = 0; j < 4; j++) {
      const int gn = col0 + tx * 4 + j;
      if (gn < N) C[(long)gm * N + gn] = acc[i][j];
    }
  }
}

// ---------------------------------------------------------------------------
// Row L2-norm inverse: inv_n[row] = 1 / (||R[row,:]|| + EPS)
// ---------------------------------------------------------------------------
__global__ __launch_bounds__(256) void row_norm_inv(
    const float* __restrict__ R, float* __restrict__ inv_n, int M, int K) {
  __shared__ float red[256];
  const int row = blockIdx.x;
  float s = 0.f;
  for (int j = threadIdx.x; j < K; j += 256) {
    const float v = R[(long)row * K + j];
    s = fmaf(v, v, s);
  }
  red[threadIdx.x] = s;
  __syncthreads();
  for (int o = 128; o > 0; o >>= 1) {
    if (threadIdx.x < o) red[threadIdx.x] += red[threadIdx.x + o];
    __syncthreads();
  }
  if (threadIdx.x == 0) inv_n[row] = 1.f / (sqrtf(red[0]) + EPS);
}

// Column L2-norm inverse: inv_n[col] = 1 / (||R[:,col]|| + EPS); coalesced.
__global__ __launch_bounds__(256) void col_norm_inv(
    const float* __restrict__ R, float* __restrict__ inv_n, int M, int K) {
  const int j = blockIdx.x * 256 + threadIdx.x;
  if (j >= K) return;
  float s = 0.f;
  for (int i = 0; i < M; i++) {
    const float v = R[(long)i * K + j];
    s = fmaf(v, v, s);
  }
  inv_n[j] = 1.f / (sqrtf(s) + EPS);
}

// ---------------------------------------------------------------------------
// Per-row top-k of scaled gram (cosine sims), self excluded, scatter into adj.
// One 256-thread block per row. Row staged in dynamic LDS (scaled); iterative
// argmax with lazy per-thread rescans. Tie-break: smaller index wins (matches
// jax.lax.top_k stability).
// ---------------------------------------------------------------------------
__global__ __launch_bounds__(256) void topk_kernel(
    const float* __restrict__ G, const float* __restrict__ inv_n,
    float* __restrict__ adj, int n, const int* __restrict__ kptr) {
  extern __shared__ float rowv[];  // n floats
  __shared__ float redv[256];
  __shared__ int redi[256];
  __shared__ int sbi;

  const int row = blockIdx.x;
  const int tid = threadIdx.x;
  const int k = *kptr;
  const float invr = inv_n[row];

  for (int j = tid; j < n; j += 256) {
    rowv[j] = (j == row) ? -INFINITY : G[(long)row * n + j] * invr * inv_n[j];
  }
  __syncthreads();

  // per-thread local argmax over strided ownership (j % 256 == tid)
  float lv = -INFINITY;
  int li = n;
  for (int j = tid; j < n; j += 256) {
    const float v = rowv[j];
    if (v > lv || (v == lv && j < li)) { lv = v; li = j; }
  }

  for (int t = 0; t < k; t++) {
    redv[tid] = lv;
    redi[tid] = li;
    __syncthreads();
    for (int o = 128; o > 0; o >>= 1) {
      if (tid < o) {
        const float v2 = redv[tid + o];
        const int i2 = redi[tid + o];
        if (v2 > redv[tid] || (v2 == redv[tid] && i2 < redi[tid])) {
          redv[tid] = v2;
          redi[tid] = i2;
        }
      }
      __syncthreads();
    }
    if (tid == 0) {
      const int bi = redi[0];
      adj[(long)row * n + bi] = redv[0];
      rowv[bi] = -INFINITY;
      sbi = bi;
    }
    __syncthreads();
    const int bi = sbi;
    if ((bi & 255) == tid) {  // owner of the removed element rescans
      lv = -INFINITY;
      li = n;
      for (int j = tid; j < n; j += 256) {
        const float v = rowv[j];
        if (v > lv || (v == lv && j < li)) { lv = v; li = j; }
      }
    }
    __syncthreads();
  }
}

// ---------------------------------------------------------------------------
// In-place symmetrize: A = (A + A^T) / 2. Each (i<j) pair handled by 1 thread.
// ---------------------------------------------------------------------------
__global__ __launch_bounds__(256) void symmetrize_kernel(float* __restrict__ A,
                                                         int n) {
  const long idx = (long)blockIdx.x * 256 + threadIdx.x;
  if (idx >= (long)n * n) return;
  const int i = (int)(idx / n);
  const int j = (int)(idx % n);
  if (j > i) {
    const float a = A[(long)i * n + j];
    const float b = A[(long)j * n + i];
    const float m = 0.5f * (a + b);
    A[(long)i * n + j] = m;
    A[(long)j * n + i] = m;
  }
}

__global__ __launch_bounds__(256) void row_sum_kernel(
    const float* __restrict__ A, float* __restrict__ s, int n) {
  __shared__ float red[256];
  const int row = blockIdx.x;
  float acc = 0.f;
  for (int j = threadIdx.x; j < n; j += 256) acc += A[(long)row * n + j];
  red[threadIdx.x] = acc;
  __syncthreads();
  for (int o = 128; o > 0; o >>= 1) {
    if (threadIdx.x < o) red[threadIdx.x] += red[threadIdx.x + o];
    __syncthreads();
  }
  if (threadIdx.x == 0) s[row] = red[0];
}

// s[i] = 1/sqrt(s[i] + EPS), in place
__global__ __launch_bounds__(256) void invsqrt_eps_kernel(float* __restrict__ s,
                                                          int n) {
  const int i = blockIdx.x * 256 + threadIdx.x;
  if (i < n) s[i] = 1.f / sqrtf(s[i] + EPS);
}

// A[i,j] *= s[i] * s[j]
__global__ __launch_bounds__(256) void sym_scale_kernel(
    float* __restrict__ A, const float* __restrict__ s, int n) {
  const long idx = (long)blockIdx.x * 256 + threadIdx.x;
  if (idx >= (long)n * n) return;
  const int i = (int)(idx / n);
  const int j = (int)(idx % n);
  A[idx] *= s[i] * s[j];
}

// ---------------------------------------------------------------------------
extern "C" void kernel_launch(void* const* d_in, const int* in_sizes, int n_in,
                              void* d_out, int out_size, void* d_ws,
                              size_t ws_size, hipStream_t stream) {
  const float* R = (const float*)d_in[0];        // [6000, 4000] fp32
  const int* k_users_p = (const int*)d_in[1];    // scalar (50)
  const int* k_items_p = (const int*)d_in[2];    // scalar (20)
  float* out = (float*)d_out;                    // [6000, 4000] fp32

  const int NU = N_USERS, NI = N_ITEMS;

  // Workspace layout (bytes):
  //  [0,            144e6)  Sbuf: user gram (later: item gram in [0,64e6),
  //                               item adjacency in [64e6,128e6))
  //  [144e6,        288e6)  adjU
  //  [288e6,        384e6)  Tbuf = R @ item_adj
  //  [384e6, ...]           invNu / invNi / sums vectors
  char* ws = (char*)d_ws;
  float* Sbuf = (float*)ws;
  float* adjU = (float*)(ws + 144000000L);
  float* adjI = (float*)(ws + 64000000L);  // overlays upper part of Sbuf region
  float* Tbuf = (float*)(ws + 288000000L);
  float* invNu = (float*)(ws + 384000000L);
  float* invNi = (float*)(ws + 384024000L);
  float* sums = (float*)(ws + 384040000L);

  // ---- norms ----
  row_norm_inv<<<NU, 256, 0, stream>>>(R, invNu, NU, NI);
  col_norm_inv<<<(NI + 255) / 256, 256, 0, stream>>>(R, invNi, NU, NI);

  // ---- user graph ----
  {
    dim3 grid((NU + 63) / 64, (NU + 63) / 64);
    gemm_kernel<0, 1><<<grid, 256, 0, stream>>>(R, R, Sbuf, NU, NU, NI);
  }
  hipMemsetAsync(adjU, 0, (long)NU * NU * sizeof(float), stream);
  topk_kernel<<<NU, 256, NU * sizeof(float), stream>>>(Sbuf, invNu, adjU, NU,
                                                       k_users_p);
  {
    const long tot = (long)NU * NU;
    symmetrize_kernel<<<(tot + 255) / 256, 256, 0, stream>>>(adjU, NU);
    row_sum_kernel<<<NU, 256, 0, stream>>>(adjU, sums, NU);
    invsqrt_eps_kernel<<<(NU + 255) / 256, 256, 0, stream>>>(sums, NU);
    sym_scale_kernel<<<(tot + 255) / 256, 256, 0, stream>>>(adjU, sums, NU);
  }

  // ---- item graph ----
  {
    dim3 grid((NI + 63) / 64, (NI + 63) / 64);
    gemm_kernel<1, 0><<<grid, 256, 0, stream>>>(R, R, Sbuf, NI, NI, NU);
  }
  hipMemsetAsync(adjI, 0, (long)NI * NI * sizeof(float), stream);
  topk_kernel<<<NI, 256, NI * sizeof(float), stream>>>(Sbuf, invNi, adjI, NI,
                                                       k_items_p);
  {
    const long tot = (long)NI * NI;
    symmetrize_kernel<<<(tot + 255) / 256, 256, 0, stream>>>(adjI, NI);
    row_sum_kernel<<<NI, 256, 0, stream>>>(adjI, sums, NI);
    invsqrt_eps_kernel<<<(NI + 255) / 256, 256, 0, stream>>>(sums, NI);
    sym_scale_kernel<<<(tot + 255) / 256, 256, 0, stream>>>(adjI, sums, NI);
  }

  // ---- propagation: out = adjU @ (R @ adjI) ----
  {
    dim3 grid((NI + 63) / 64, (NU + 63) / 64);
    gemm_kernel<0, 0><<<grid, 256, 0, stream>>>(R, adjI, Tbuf, NU, NI, NI);
    gemm_kernel<0, 0><<<grid, 256, 0, stream>>>(adjU, Tbuf, out, NU, NI, NU);
  }
}

// Round 2
// 6716.997 us; speedup vs baseline: 2.9843x; 2.9843x over previous
//
#include <hip/hip_runtime.h>
#include <math.h>

#define EPS 1e-8f

constexpr int N_USERS = 6000;
constexpr int N_ITEMS = 4000;
constexpr int NU_P = 6016;  // 47 * 128
constexpr int NI_P = 4096;  // 32 * 128

typedef __bf16 bf16_8 __attribute__((ext_vector_type(8)));
typedef float f32_4 __attribute__((ext_vector_type(4)));

// ---------------------------------------------------------------------------
// async global->LDS, 16B per lane
// ---------------------------------------------------------------------------
__device__ __forceinline__ void stage16(const __bf16* g, __bf16* l) {
  __builtin_amdgcn_global_load_lds(
      (const __attribute__((address_space(1))) void*)g,
      (__attribute__((address_space(3))) void*)l, 16, 0, 0);
}

// ---------------------------------------------------------------------------
// MFMA GEMM: C[M,N] fp32 = A @ B^T (+split terms), A [M,K] bf16 row-major
// (k-contiguous), B [N,K] bf16 row-major. lda/ldb are padded strides; buffers
// must be padded so that any row in [0, 128*gridDim) is readable (zero pad).
// SPLIT=1: C = Ah Bh^T + Ah Bl^T + Al Bh^T  (bf16 hi/lo split, ~fp32 accuracy)
// 128x128 tile, BK=32, 4 waves, each wave 64x64 via 4x4 of 16x16x32 MFMA.
// ---------------------------------------------------------------------------
template <int SPLIT>
__global__ __launch_bounds__(256) void mfma_gemm_bt(
    const __bf16* __restrict__ Ah, const __bf16* __restrict__ Al,
    const __bf16* __restrict__ Bh, const __bf16* __restrict__ Bl,
    float* __restrict__ C, int M, int N, int K, long lda, long ldb, long ldc) {
  __shared__ __bf16 sAh[128 * 32];
  __shared__ __bf16 sBh[128 * 32];
  __shared__ __bf16 sAl[SPLIT ? 128 * 32 : 8];
  __shared__ __bf16 sBl[SPLIT ? 128 * 32 : 8];

  const int tid = threadIdx.x;
  const int lane = tid & 63;
  const int wave = tid >> 6;
  const int wm = (wave >> 1) * 64;
  const int wn = (wave & 1) * 64;
  const int lm = lane & 15;   // m/n within 16-tile
  const int kg = lane >> 4;   // k-group 0..3 (8 bf16 each)
  const long row0 = (long)blockIdx.y * 128;
  const long col0 = (long)blockIdx.x * 128;

  f32_4 acc[4][4];
#pragma unroll
  for (int i = 0; i < 4; i++)
#pragma unroll
    for (int j = 0; j < 4; j++) acc[i][j] = (f32_4){0.f, 0.f, 0.f, 0.f};

  // each thread stages two 16B chunks per tile; chunk c -> row c>>2, kchunk c&3
  const int c0 = tid, c1 = tid + 256;
  const int r0c = c0 >> 2, k0c = c0 & 3;
  const int r1c = c1 >> 2, k1c = c1 & 3;

  for (int k0 = 0; k0 < K; k0 += 32) {
    stage16(Ah + (row0 + r0c) * lda + k0 + k0c * 8, sAh + c0 * 8);
    stage16(Ah + (row0 + r1c) * lda + k0 + k1c * 8, sAh + c1 * 8);
    stage16(Bh + (col0 + r0c) * ldb + k0 + k0c * 8, sBh + c0 * 8);
    stage16(Bh + (col0 + r1c) * ldb + k0 + k1c * 8, sBh + c1 * 8);
    if (SPLIT) {
      stage16(Al + (row0 + r0c) * lda + k0 + k0c * 8, sAl + c0 * 8);
      stage16(Al + (row0 + r1c) * lda + k0 + k1c * 8, sAl + c1 * 8);
      stage16(Bl + (col0 + r0c) * ldb + k0 + k0c * 8, sBl + c0 * 8);
      stage16(Bl + (col0 + r1c) * ldb + k0 + k1c * 8, sBl + c1 * 8);
    }
    __syncthreads();

    bf16_8 ah[4], bh[4], alo[4], blo[4];
#pragma unroll
    for (int i = 0; i < 4; i++) {
      ah[i] = *(const bf16_8*)&sAh[(wm + i * 16 + lm) * 32 + kg * 8];
      bh[i] = *(const bf16_8*)&sBh[(wn + i * 16 + lm) * 32 + kg * 8];
    }
    if (SPLIT) {
#pragma unroll
      for (int i = 0; i < 4; i++) {
        alo[i] = *(const bf16_8*)&sAl[(wm + i * 16 + lm) * 32 + kg * 8];
        blo[i] = *(const bf16_8*)&sBl[(wn + i * 16 + lm) * 32 + kg * 8];
      }
    }
#pragma unroll
    for (int i = 0; i < 4; i++)
#pragma unroll
      for (int j = 0; j < 4; j++) {
        acc[i][j] = __builtin_amdgcn_mfma_f32_16x16x32_bf16(ah[i], bh[j],
                                                            acc[i][j], 0, 0, 0);
        if (SPLIT) {
          acc[i][j] = __builtin_amdgcn_mfma_f32_16x16x32_bf16(
              ah[i], blo[j], acc[i][j], 0, 0, 0);
          acc[i][j] = __builtin_amdgcn_mfma_f32_16x16x32_bf16(
              alo[i], bh[j], acc[i][j], 0, 0, 0);
        }
      }
    __syncthreads();
  }

  // epilogue: C/D layout col=lane&15, row=(lane>>4)*4+reg [m89/m91 verified]
#pragma unroll
  for (int i = 0; i < 4; i++)
#pragma unroll
    for (int j = 0; j < 4; j++)
#pragma unroll
      for (int r = 0; r < 4; r++) {
        const long gm = row0 + wm + i * 16 + kg * 4 + r;
        const long gn = col0 + wn + j * 16 + lm;
        if (gm < M && gn < N) C[gm * ldc + gn] = acc[i][j][r];
      }
}

// ---------------------------------------------------------------------------
// R [M,N] fp32 -> padded hi/lo bf16 [gridDim.y, Np]
// ---------------------------------------------------------------------------
__global__ __launch_bounds__(256) void pad_split_kernel(
    const float* __restrict__ R, __bf16* __restrict__ H, __bf16* __restrict__ L,
    int M, int N, int Np) {
  const int r = blockIdx.y;
  const int c = blockIdx.x * 256 + threadIdx.x;
  if (c >= Np) return;
  const float v = (r < M && c < N) ? R[(long)r * N + c] : 0.f;
  const __bf16 h = (__bf16)v;
  H[(long)r * Np + c] = h;
  L[(long)r * Np + c] = (__bf16)(v - (float)h);
}

// ---------------------------------------------------------------------------
// Transpose fp32 [M,N] -> padded bf16 [Np, Mp] (hi + optional lo), LDS-tiled.
// Grid: x = Np/32, y = Mp/32 (covers full padded output; pad reads -> 0).
// ---------------------------------------------------------------------------
__global__ __launch_bounds__(256) void transpose_split_kernel(
    const float* __restrict__ R, __bf16* __restrict__ Th,
    __bf16* __restrict__ Tl, int M, int N, int Mp, int Np) {
  __shared__ float tile[32][33];
  const int tx = threadIdx.x & 31;
  const int ty = threadIdx.x >> 5;  // 0..7
  const int ri = blockIdx.y * 32;   // input row base (M dim)
  const int ci = blockIdx.x * 32;   // input col base (N dim)
#pragma unroll
  for (int k = 0; k < 4; k++) {
    const int r = ri + ty + k * 8, c = ci + tx;
    tile[ty + k * 8][tx] = (r < M && c < N) ? R[(long)r * N + c] : 0.f;
  }
  __syncthreads();
#pragma unroll
  for (int k = 0; k < 4; k++) {
    const int orow = ci + ty + k * 8;  // N-dim index
    const int ocol = ri + tx;          // M-dim index
    if (orow < Np && ocol < Mp) {
      const float v = tile[tx][ty + k * 8];
      const __bf16 h = (__bf16)v;
      Th[(long)orow * Mp + ocol] = h;
      if (Tl) Tl[(long)orow * Mp + ocol] = (__bf16)(v - (float)h);
    }
  }
}

// fp32 [n,n] -> padded bf16 [np,np]
__global__ __launch_bounds__(256) void convert_pad_kernel(
    const float* __restrict__ A, __bf16* __restrict__ B, int n, int np) {
  const int r = blockIdx.y;
  const int c = blockIdx.x * 256 + threadIdx.x;
  if (c >= np) return;
  B[(long)r * np + c] = (__bf16)((r < n && c < n) ? A[(long)r * n + c] : 0.f);
}

// ---------------------------------------------------------------------------
// norms
// ---------------------------------------------------------------------------
__global__ __launch_bounds__(256) void row_norm_inv(
    const float* __restrict__ R, float* __restrict__ inv_n, int M, int K) {
  __shared__ float red[256];
  const int row = blockIdx.x;
  float s = 0.f;
  for (int j = threadIdx.x; j < K; j += 256) {
    const float v = R[(long)row * K + j];
    s = fmaf(v, v, s);
  }
  red[threadIdx.x] = s;
  __syncthreads();
  for (int o = 128; o > 0; o >>= 1) {
    if (threadIdx.x < o) red[threadIdx.x] += red[threadIdx.x + o];
    __syncthreads();
  }
  if (threadIdx.x == 0) inv_n[row] = 1.f / (sqrtf(red[0]) + EPS);
}

__global__ __launch_bounds__(256) void col_norm_inv(
    const float* __restrict__ R, float* __restrict__ inv_n, int M, int K) {
  const int j = blockIdx.x * 256 + threadIdx.x;
  if (j >= K) return;
  float s = 0.f;
  for (int i = 0; i < M; i++) {
    const float v = R[(long)i * K + j];
    s = fmaf(v, v, s);
  }
  inv_n[j] = 1.f / (sqrtf(s) + EPS);
}

// ---------------------------------------------------------------------------
// Per-row top-k of scaled gram, self excluded, scatter into adj (pre-zeroed).
// ---------------------------------------------------------------------------
__global__ __launch_bounds__(256) void topk_kernel(
    const float* __restrict__ G, const float* __restrict__ inv_n,
    float* __restrict__ adj, int n, const int* __restrict__ kptr) {
  extern __shared__ float rowv[];  // n floats
  __shared__ float redv[256];
  __shared__ int redi[256];
  __shared__ int sbi;

  const int row = blockIdx.x;
  const int tid = threadIdx.x;
  const int k = *kptr;
  const float invr = inv_n[row];

  for (int j = tid; j < n; j += 256) {
    rowv[j] = (j == row) ? -INFINITY : G[(long)row * n + j] * invr * inv_n[j];
  }
  __syncthreads();

  float lv = -INFINITY;
  int li = n;
  for (int j = tid; j < n; j += 256) {
    const float v = rowv[j];
    if (v > lv || (v == lv && j < li)) { lv = v; li = j; }
  }

  for (int t = 0; t < k; t++) {
    redv[tid] = lv;
    redi[tid] = li;
    __syncthreads();
    for (int o = 128; o > 0; o >>= 1) {
      if (tid < o) {
        const float v2 = redv[tid + o];
        const int i2 = redi[tid + o];
        if (v2 > redv[tid] || (v2 == redv[tid] && i2 < redi[tid])) {
          redv[tid] = v2;
          redi[tid] = i2;
        }
      }
      __syncthreads();
    }
    if (tid == 0) {
      const int bi = redi[0];
      adj[(long)row * n + bi] = redv[0];
      rowv[bi] = -INFINITY;
      sbi = bi;
    }
    __syncthreads();
    const int bi = sbi;
    if ((bi & 255) == tid) {
      lv = -INFINITY;
      li = n;
      for (int j = tid; j < n; j += 256) {
        const float v = rowv[j];
        if (v > lv || (v == lv && j < li)) { lv = v; li = j; }
      }
    }
    __syncthreads();
  }
}

// ---------------------------------------------------------------------------
__global__ __launch_bounds__(256) void symmetrize_kernel(float* __restrict__ A,
                                                         int n) {
  const long idx = (long)blockIdx.x * 256 + threadIdx.x;
  if (idx >= (long)n * n) return;
  const int i = (int)(idx / n);
  const int j = (int)(idx % n);
  if (j > i) {
    const float a = A[(long)i * n + j];
    const float b = A[(long)j * n + i];
    const float m = 0.5f * (a + b);
    A[(long)i * n + j] = m;
    A[(long)j * n + i] = m;
  }
}

__global__ __launch_bounds__(256) void row_sum_kernel(
    const float* __restrict__ A, float* __restrict__ s, int n) {
  __shared__ float red[256];
  const int row = blockIdx.x;
  float acc = 0.f;
  for (int j = threadIdx.x; j < n; j += 256) acc += A[(long)row * n + j];
  red[threadIdx.x] = acc;
  __syncthreads();
  for (int o = 128; o > 0; o >>= 1) {
    if (threadIdx.x < o) red[threadIdx.x] += red[threadIdx.x + o];
    __syncthreads();
  }
  if (threadIdx.x == 0) s[row] = red[0];
}

__global__ __launch_bounds__(256) void invsqrt_eps_kernel(float* __restrict__ s,
                                                          int n) {
  const int i = blockIdx.x * 256 + threadIdx.x;
  if (i < n) s[i] = 1.f / sqrtf(s[i] + EPS);
}

__global__ __launch_bounds__(256) void sym_scale_kernel(
    float* __restrict__ A, const float* __restrict__ s, int n) {
  const long idx = (long)blockIdx.x * 256 + threadIdx.x;
  if (idx >= (long)n * n) return;
  const int i = (int)(idx / n);
  const int j = (int)(idx % n);
  A[idx] *= s[i] * s[j];
}

// ---------------------------------------------------------------------------
extern "C" void kernel_launch(void* const* d_in, const int* in_sizes, int n_in,
                              void* d_out, int out_size, void* d_ws,
                              size_t ws_size, hipStream_t stream) {
  const float* R = (const float*)d_in[0];
  const int* k_users_p = (const int*)d_in[1];
  const int* k_items_p = (const int*)d_in[2];
  float* out = (float*)d_out;

  // ---- workspace layout (peak 364.4 MB; lifetimes annotated) ----
  char* ws = (char*)d_ws;
  float* invNu = (float*)(ws + 0);          // 24 KB
  float* invNi = (float*)(ws + 24576);      // 16 KB
  float* sums = (float*)(ws + 49152);       // 24 KB
  __bf16* Rh = (__bf16*)(ws + 100000L);     // [NU_P,NI_P] until prop1
  __bf16* Rl = (__bf16*)(ws + 49400000L);   // [NU_P,NI_P] until user gram
  float* adjU = (float*)(ws + 49400000L);   // [6000^2] f32, after Rl dead
  float* Su = (float*)(ws + 193400000L);    // [6000^2] f32, until user topk
  __bf16* adjUb = (__bf16*)(ws + 193400000L);  // [NU_P^2], after Su dead
  __bf16* RhT = (__bf16*)(ws + 265800000L);    // [NI_P,NU_P], until item gram
  __bf16* RlT = (__bf16*)(ws + 315100000L);    // [NI_P,NU_P], until item gram
  float* Si = (float*)(ws + 49400000L);        // [4000^2], after adjU dead
  float* adjI = (float*)(ws + 113400000L);     // [4000^2] f32
  __bf16* adjIb = (__bf16*)(ws + 265800000L);  // [NI_P^2], after RhT dead
  float* Tbuf = (float*)(ws + 49400000L);      // [NU_P,NI_P] f32, after Si dead
  __bf16* Tt = (__bf16*)(ws + 100000L);        // [NI_P,NU_P], after Rh dead

  const int NU = N_USERS, NI = N_ITEMS;

  // ---- norms ----
  row_norm_inv<<<NU, 256, 0, stream>>>(R, invNu, NU, NI);
  col_norm_inv<<<(NI + 255) / 256, 256, 0, stream>>>(R, invNi, NU, NI);

  // ---- split-convert R ----
  pad_split_kernel<<<dim3(NI_P / 256, NU_P), 256, 0, stream>>>(R, Rh, Rl, NU,
                                                               NI, NI_P);

  // ---- user gram (split precision): Su = R Rt ----
  mfma_gemm_bt<1><<<dim3(47, 47), 256, 0, stream>>>(
      Rh, Rl, Rh, Rl, Su, NU, NU, NI_P, NI_P, NI_P, NU);

  // ---- user top-k + normalize ----
  hipMemsetAsync(adjU, 0, (long)NU * NU * sizeof(float), stream);
  topk_kernel<<<NU, 256, NU * sizeof(float), stream>>>(Su, invNu, adjU, NU,
                                                       k_users_p);
  {
    const long tot = (long)NU * NU;
    symmetrize_kernel<<<(tot + 255) / 256, 256, 0, stream>>>(adjU, NU);
    row_sum_kernel<<<NU, 256, 0, stream>>>(adjU, sums, NU);
    invsqrt_eps_kernel<<<(NU + 255) / 256, 256, 0, stream>>>(sums, NU);
    sym_scale_kernel<<<(tot + 255) / 256, 256, 0, stream>>>(adjU, sums, NU);
  }
  convert_pad_kernel<<<dim3((NU_P + 255) / 256, NU_P), 256, 0, stream>>>(
      adjU, adjUb, NU, NU_P);

  // ---- item gram (split precision): Si = Rt R via RhT/RlT ----
  transpose_split_kernel<<<dim3(NI_P / 32, NU_P / 32), 256, 0, stream>>>(
      R, RhT, RlT, NU, NI, NU_P, NI_P);
  mfma_gemm_bt<1><<<dim3(32, 32), 256, 0, stream>>>(
      RhT, RlT, RhT, RlT, Si, NI, NI, NU_P, NU_P, NU_P, NI);

  // ---- item top-k + normalize ----
  hipMemsetAsync(adjI, 0, (long)NI * NI * sizeof(float), stream);
  topk_kernel<<<NI, 256, NI * sizeof(float), stream>>>(Si, invNi, adjI, NI,
                                                       k_items_p);
  {
    const long tot = (long)NI * NI;
    symmetrize_kernel<<<(tot + 255) / 256, 256, 0, stream>>>(adjI, NI);
    row_sum_kernel<<<NI, 256, 0, stream>>>(adjI, sums, NI);
    invsqrt_eps_kernel<<<(NI + 255) / 256, 256, 0, stream>>>(sums, NI);
    sym_scale_kernel<<<(tot + 255) / 256, 256, 0, stream>>>(adjI, sums, NI);
  }
  convert_pad_kernel<<<dim3(NI_P / 256, NI_P), 256, 0, stream>>>(adjI, adjIb,
                                                                 NI, NI_P);

  // ---- prop1: T = R @ adjI  (adjI symmetric -> BT form directly) ----
  mfma_gemm_bt<0><<<dim3(32, 47), 256, 0, stream>>>(
      Rh, nullptr, adjIb, nullptr, Tbuf, NU_P, NI_P, NI_P, NI_P, NI_P, NI_P);

  // ---- transpose T for prop2 ----
  transpose_split_kernel<<<dim3(NI_P / 32, NU_P / 32), 256, 0, stream>>>(
      Tbuf, Tt, nullptr, NU_P, NI_P, NU_P, NI_P);

  // ---- prop2: out = adjU @ T ----
  mfma_gemm_bt<0><<<dim3(32, 47), 256, 0, stream>>>(
      adjUb, nullptr, Tt, nullptr, out, NU, NI, NU_P, NU_P, NU_P, NI);
}

// Round 3
// 5226.822 us; speedup vs baseline: 3.8351x; 1.2851x over previous
//
#include <hip/hip_runtime.h>
#include <math.h>

#define EPS 1e-8f

constexpr int N_USERS = 6000;
constexpr int N_ITEMS = 4000;
constexpr int NU_P = 6016;  // 47 * 128
constexpr int NI_P = 4096;  // 32 * 128

typedef __bf16 bf16_8 __attribute__((ext_vector_type(8)));
typedef float f32_4 __attribute__((ext_vector_type(4)));

// ---------------------------------------------------------------------------
__device__ __forceinline__ void stage16(const __bf16* g, __bf16* l) {
  __builtin_amdgcn_global_load_lds(
      (const __attribute__((address_space(1))) void*)g,
      (__attribute__((address_space(3))) void*)l, 16, 0, 0);
}

// triangular decode: p -> (by, bx) with bx <= by
__device__ __forceinline__ void tri_decode(int p, int& by, int& bx) {
  int r = (int)((sqrtf(8.f * p + 1.f) - 1.f) * 0.5f);
  while ((r + 1) * (r + 2) / 2 <= p) r++;
  while (r * (r + 1) / 2 > p) r--;
  by = r;
  bx = p - r * (r + 1) / 2;
}

// grouped decode (G=8 rows, column-major within band) for L2 locality
__device__ __forceinline__ void grp_decode(int p, int nby, int nbx, int& by,
                                           int& bx) {
  const int G = 8;
  const int wide = G * nbx;
  const int band = p / wide;
  const int rem = p - band * wide;
  const int h = min(G, nby - band * G);
  by = band * G + rem % h;
  bx = rem / h;
}

// ---------------------------------------------------------------------------
// MFMA GEMM, 1D grid. C[M,N] = A @ B^T. A [M,K] bf16 k-contiguous (lda), B
// [N,K] (ldb), padded so any staged row is readable. SPLIT: 3-term bf16 hi/lo
// (~fp32). TRI: triangular grid decode (A==B symmetric gram, lower blocks).
// OUTBF16: store bf16 to Cb instead of fp32 to Cf.
// LDS layout swizzle: chunk for (row r, kchunk j) sits at slot (j+(r>>1))&3,
// applied via the *global* source address at stage time (LDS dest must stay
// base + lane*16 per global_load_lds semantics). Gives 2 lanes/bank (free).
// ---------------------------------------------------------------------------
template <int SPLIT, int TRI, int OUTBF16>
__global__ __launch_bounds__(256) void mfma_gemm(
    const __bf16* __restrict__ Ah, const __bf16* __restrict__ Al,
    const __bf16* __restrict__ Bh, const __bf16* __restrict__ Bl,
    float* __restrict__ Cf, __bf16* __restrict__ Cb, int M, int N, int K,
    long lda, long ldb, long ldc, int nby, int nbx) {
  __shared__ __bf16 sAh[128 * 32];
  __shared__ __bf16 sBh[128 * 32];
  __shared__ __bf16 sAl[SPLIT ? 128 * 32 : 8];
  __shared__ __bf16 sBl[SPLIT ? 128 * 32 : 8];

  int by, bx;
  if (TRI)
    tri_decode(blockIdx.x, by, bx);
  else
    grp_decode(blockIdx.x, nby, nbx, by, bx);

  const int tid = threadIdx.x;
  const int lane = tid & 63;
  const int wave = tid >> 6;
  const int wm = (wave >> 1) * 64;
  const int wn = (wave & 1) * 64;
  const int lm = lane & 15;
  const int kg = lane >> 4;
  const long row0 = (long)by * 128;
  const long col0 = (long)bx * 128;

  f32_4 acc[4][4];
#pragma unroll
  for (int i = 0; i < 4; i++)
#pragma unroll
    for (int j = 0; j < 4; j++) acc[i][j] = (f32_4){0.f, 0.f, 0.f, 0.f};

  // staging: chunk c -> row c>>2, LDS offset c*16B; global kchunk swizzled
  const int c0 = tid, c1 = tid + 256;
  const int r0c = c0 >> 2, j0c = ((c0 & 3) - (r0c >> 1)) & 3;
  const int r1c = c1 >> 2, j1c = ((c1 & 3) - (r1c >> 1)) & 3;

  for (int k0 = 0; k0 < K; k0 += 32) {
    stage16(Ah + (row0 + r0c) * lda + k0 + j0c * 8, sAh + c0 * 8);
    stage16(Ah + (row0 + r1c) * lda + k0 + j1c * 8, sAh + c1 * 8);
    stage16(Bh + (col0 + r0c) * ldb + k0 + j0c * 8, sBh + c0 * 8);
    stage16(Bh + (col0 + r1c) * ldb + k0 + j1c * 8, sBh + c1 * 8);
    if (SPLIT) {
      stage16(Al + (row0 + r0c) * lda + k0 + j0c * 8, sAl + c0 * 8);
      stage16(Al + (row0 + r1c) * lda + k0 + j1c * 8, sAl + c1 * 8);
      stage16(Bl + (col0 + r0c) * ldb + k0 + j0c * 8, sBl + c0 * 8);
      stage16(Bl + (col0 + r1c) * ldb + k0 + j1c * 8, sBl + c1 * 8);
    }
    __syncthreads();

    bf16_8 ah[4], bh[4], alo[4], blo[4];
#pragma unroll
    for (int i = 0; i < 4; i++) {
      const int ra = wm + i * 16 + lm;
      const int rb = wn + i * 16 + lm;
      ah[i] = *(const bf16_8*)&sAh[(ra * 4 + ((kg + (ra >> 1)) & 3)) * 8];
      bh[i] = *(const bf16_8*)&sBh[(rb * 4 + ((kg + (rb >> 1)) & 3)) * 8];
      if (SPLIT) {
        alo[i] = *(const bf16_8*)&sAl[(ra * 4 + ((kg + (ra >> 1)) & 3)) * 8];
        blo[i] = *(const bf16_8*)&sBl[(rb * 4 + ((kg + (rb >> 1)) & 3)) * 8];
      }
    }
#pragma unroll
    for (int i = 0; i < 4; i++)
#pragma unroll
      for (int j = 0; j < 4; j++) {
        acc[i][j] = __builtin_amdgcn_mfma_f32_16x16x32_bf16(ah[i], bh[j],
                                                            acc[i][j], 0, 0, 0);
        if (SPLIT) {
          acc[i][j] = __builtin_amdgcn_mfma_f32_16x16x32_bf16(
              ah[i], blo[j], acc[i][j], 0, 0, 0);
          acc[i][j] = __builtin_amdgcn_mfma_f32_16x16x32_bf16(
              alo[i], bh[j], acc[i][j], 0, 0, 0);
        }
      }
    __syncthreads();
  }

  // epilogue: C/D layout col=lane&15, row=(lane>>4)*4+reg
#pragma unroll
  for (int i = 0; i < 4; i++)
#pragma unroll
    for (int j = 0; j < 4; j++)
#pragma unroll
      for (int r = 0; r < 4; r++) {
        const long gm = row0 + wm + i * 16 + kg * 4 + r;
        const long gn = col0 + wn + j * 16 + lm;
        if (gm < M && gn < N) {
          if (OUTBF16)
            Cb[gm * ldc + gn] = (__bf16)acc[i][j][r];
          else
            Cf[gm * ldc + gn] = acc[i][j][r];
        }
      }
}

// ---------------------------------------------------------------------------
// R [M,N] fp32 -> padded hi/lo bf16 [gridDim.y, Np]
// ---------------------------------------------------------------------------
__global__ __launch_bounds__(256) void pad_split_kernel(
    const float* __restrict__ R, __bf16* __restrict__ H, __bf16* __restrict__ L,
    int M, int N, int Np) {
  const int r = blockIdx.y;
  const int c = blockIdx.x * 256 + threadIdx.x;
  if (c >= Np) return;
  const float v = (r < M && c < N) ? R[(long)r * N + c] : 0.f;
  const __bf16 h = (__bf16)v;
  H[(long)r * Np + c] = h;
  L[(long)r * Np + c] = (__bf16)(v - (float)h);
}

// ---------------------------------------------------------------------------
// Transpose fp32 [M,N] -> padded bf16 [Np, Mp] hi/lo, LDS-tiled.
// ---------------------------------------------------------------------------
__global__ __launch_bounds__(256) void transpose_split_kernel(
    const float* __restrict__ R, __bf16* __restrict__ Th,
    __bf16* __restrict__ Tl, int M, int N, int Mp, int Np) {
  __shared__ float tile[32][33];
  const int tx = threadIdx.x & 31;
  const int ty = threadIdx.x >> 5;
  const int ri = blockIdx.y * 32;
  const int ci = blockIdx.x * 32;
#pragma unroll
  for (int k = 0; k < 4; k++) {
    const int r = ri + ty + k * 8, c = ci + tx;
    tile[ty + k * 8][tx] = (r < M && c < N) ? R[(long)r * N + c] : 0.f;
  }
  __syncthreads();
#pragma unroll
  for (int k = 0; k < 4; k++) {
    const int orow = ci + ty + k * 8;
    const int ocol = ri + tx;
    if (orow < Np && ocol < Mp) {
      const float v = tile[tx][ty + k * 8];
      Th[(long)orow * Mp + ocol] = (__bf16)v;
      if (Tl) Tl[(long)orow * Mp + ocol] = (__bf16)(v - (float)(__bf16)v);
    }
  }
}

// ---------------------------------------------------------------------------
// Mirror lower triangle of fp32 S [n,n] into strict upper, 32x32 tile pairs.
// Grid: T*(T-1)/2 blocks, T = ceil(n/32). Diagonal 32-tiles were written by
// the (full) diagonal 128-blocks of the triangular GEMM.
// ---------------------------------------------------------------------------
__global__ __launch_bounds__(256) void mirror_kernel(float* __restrict__ S,
                                                     int n) {
  __shared__ float tile[32][33];
  int by, bx;
  tri_decode(blockIdx.x, by, bx);
  const int tj = by + 1, ti = bx;  // tj > ti
  const int sr = tj * 32, sc = ti * 32;
  const int tx = threadIdx.x & 31;
  const int ty = threadIdx.x >> 5;
#pragma unroll
  for (int k = 0; k < 4; k++) {
    const int r = sr + ty + k * 8, c = sc + tx;
    tile[ty + k * 8][tx] = (r < n && c < n) ? S[(long)r * n + c] : 0.f;
  }
  __syncthreads();
#pragma unroll
  for (int k = 0; k < 4; k++) {
    const int r = sc + ty + k * 8, c = sr + tx;
    if (r < n && c < n) S[(long)r * n + c] = tile[tx][ty + k * 8];
  }
}

// ---------------------------------------------------------------------------
// norms
// ---------------------------------------------------------------------------
__global__ __launch_bounds__(256) void row_norm_inv(
    const float* __restrict__ R, float* __restrict__ inv_n, int M, int K) {
  __shared__ float red[256];
  const int row = blockIdx.x;
  float s = 0.f;
  for (int j = threadIdx.x; j < K; j += 256) {
    const float v = R[(long)row * K + j];
    s = fmaf(v, v, s);
  }
  red[threadIdx.x] = s;
  __syncthreads();
  for (int o = 128; o > 0; o >>= 1) {
    if (threadIdx.x < o) red[threadIdx.x] += red[threadIdx.x + o];
    __syncthreads();
  }
  if (threadIdx.x == 0) inv_n[row] = 1.f / (sqrtf(red[0]) + EPS);
}

__global__ __launch_bounds__(256) void col_norm_inv(
    const float* __restrict__ R, float* __restrict__ inv_n, int M, int K) {
  const int j = blockIdx.x * 256 + threadIdx.x;
  if (j >= K) return;
  float s = 0.f;
  for (int i = 0; i < M; i++) {
    const float v = R[(long)i * K + j];
    s = fmaf(v, v, s);
  }
  inv_n[j] = 1.f / (sqrtf(s) + EPS);
}

// ---------------------------------------------------------------------------
// Top-k, one wave64 per row. Lane-private LDS slices (j % 64 == lane), no
// barriers in the selection loop; shfl-xor butterfly argmax (ties: min idx).
// Writes bf16 adj (pre-zeroed, padded stride np), fp32 rowsum, atomic colsum.
// ---------------------------------------------------------------------------
__global__ __launch_bounds__(64) void topk_kernel(
    const float* __restrict__ G, const float* __restrict__ inv_n,
    __bf16* __restrict__ adj, float* __restrict__ rowsum,
    float* __restrict__ colsum, int n, int np, const int* __restrict__ kptr) {
  extern __shared__ float rowv[];
  const int row = blockIdx.x;
  const int lane = threadIdx.x;
  const int k = *kptr;
  const float invr = inv_n[row];

  float lv = -INFINITY;
  int li = n;
  for (int j = lane; j < n; j += 64) {
    const float v = (j == row) ? -INFINITY : G[(long)row * n + j] * invr * inv_n[j];
    rowv[j] = v;
    if (v > lv) { lv = v; li = j; }  // ascending j: first max kept on ties
  }

  float rsum = 0.f;
  for (int t = 0; t < k; t++) {
    float v = lv;
    int i = li;
#pragma unroll
    for (int off = 32; off > 0; off >>= 1) {
      const float ov = __shfl_xor(v, off);
      const int oi = __shfl_xor(i, off);
      if (ov > v || (ov == v && oi < i)) { v = ov; i = oi; }
    }
    if (lane == 0) {
      adj[(long)row * np + i] = (__bf16)v;
      atomicAdd(&colsum[i], v);
      rsum += v;
    }
    if ((i & 63) == lane) {  // owner removes + rescans its private slice
      rowv[i] = -INFINITY;
      lv = -INFINITY;
      li = n;
      for (int j = lane; j < n; j += 64) {
        const float vv = rowv[j];
        if (vv > lv) { lv = vv; li = j; }
      }
    }
  }
  if (lane == 0) rowsum[row] = rsum;
}

// f[i] = 1/sqrt(0.5*(rowsum+colsum) + EPS)
__global__ __launch_bounds__(256) void finalize_kernel(
    const float* __restrict__ rs, const float* __restrict__ cs,
    float* __restrict__ f, int n) {
  const int i = blockIdx.x * 256 + threadIdx.x;
  if (i < n) f[i] = rsqrtf(0.5f * (rs[i] + cs[i]) + EPS);
}

// in-place: adj[i,j] = adj[j,i] = 0.5*(adj[i,j]+adj[j,i]) * f[i]*f[j]
__global__ __launch_bounds__(256) void symscale_kernel(
    __bf16* __restrict__ adj, const float* __restrict__ f, int n, int np) {
  const long idx = (long)blockIdx.x * 256 + threadIdx.x;
  if (idx >= (long)np * np) return;
  const int i = (int)(idx / np);
  const int j = (int)(idx % np);
  if (j <= i || i >= n || j >= n) return;
  const float a = (float)adj[(long)i * np + j];
  const float b = (float)adj[(long)j * np + i];
  const float m = 0.5f * (a + b) * f[i] * f[j];
  adj[(long)i * np + j] = (__bf16)m;
  adj[(long)j * np + i] = (__bf16)m;
}

// ---------------------------------------------------------------------------
extern "C" void kernel_launch(void* const* d_in, const int* in_sizes, int n_in,
                              void* d_out, int out_size, void* d_ws,
                              size_t ws_size, hipStream_t stream) {
  const float* R = (const float*)d_in[0];
  const int* k_users_p = (const int*)d_in[1];
  const int* k_items_p = (const int*)d_in[2];
  float* out = (float*)d_out;
  const int NU = N_USERS, NI = N_ITEMS;

  // ---- workspace (peak ~352 MB; lifetimes ordered: item graph -> user
  // graph -> props) ----
  char* ws = (char*)d_ws;
  float* invNu = (float*)(ws + 0);        // 24 KB
  float* invNi = (float*)(ws + 32768);    // 16 KB
  float* rsU = (float*)(ws + 65536);      // 24 KB
  float* csU = (float*)(ws + 98304);      // 24 KB
  float* rsI = (float*)(ws + 131072);     // 16 KB
  float* csI = (float*)(ws + 163840);     // 16 KB
  float* fU = (float*)(ws + 196608);      // 24 KB
  float* fI = (float*)(ws + 229376);      // 16 KB
  const long MB = 1000000L;
  __bf16* Rh = (__bf16*)(ws + 1 * MB);     // [NU_P,NI_P] until prop1
  __bf16* Rl = (__bf16*)(ws + 51 * MB);    // [NU_P,NI_P] until user gram
  __bf16* Tt = (__bf16*)(ws + 51 * MB);    // [NI_P,NU_P] prop1->prop2 (on Rl)
  __bf16* RhT = (__bf16*)(ws + 101 * MB);  // [NI_P,NU_P] until item gram
  __bf16* RlT = (__bf16*)(ws + 151 * MB);  // [NI_P,NU_P] until item gram
  float* Si = (float*)(ws + 201 * MB);     // [4000^2] until item topk
  float* Su = (float*)(ws + 101 * MB);     // [6000^2] after RhT/RlT/Si dead
  __bf16* adjUb = (__bf16*)(ws + 245 * MB);  // [NU_P^2] until prop2
  __bf16* adjIb = (__bf16*)(ws + 318 * MB);  // [NI_P^2] until prop1

  // ---- norms + bf16 conversions ----
  row_norm_inv<<<NU, 256, 0, stream>>>(R, invNu, NU, NI);
  col_norm_inv<<<(NI + 255) / 256, 256, 0, stream>>>(R, invNi, NU, NI);
  pad_split_kernel<<<dim3(NI_P / 256, NU_P), 256, 0, stream>>>(R, Rh, Rl, NU,
                                                               NI, NI_P);
  transpose_split_kernel<<<dim3(NI_P / 32, NU_P / 32), 256, 0, stream>>>(
      R, RhT, RlT, NU, NI, NU_P, NI_P);

  // ================= item graph =================
  mfma_gemm<1, 1, 0><<<32 * 33 / 2, 256, 0, stream>>>(
      RhT, RlT, RhT, RlT, Si, nullptr, NI, NI, NU_P, NU_P, NU_P, NI, 32, 32);
  {
    const int T = (NI + 31) / 32;  // 125
    mirror_kernel<<<T * (T - 1) / 2, 256, 0, stream>>>(Si, NI);
  }
  hipMemsetAsync(adjIb, 0, (long)NI_P * NI_P * sizeof(__bf16), stream);
  hipMemsetAsync(csI, 0, NI * sizeof(float), stream);
  topk_kernel<<<NI, 64, NI * sizeof(float), stream>>>(Si, invNi, adjIb, rsI,
                                                      csI, NI, NI_P, k_items_p);
  finalize_kernel<<<(NI + 255) / 256, 256, 0, stream>>>(rsI, csI, fI, NI);
  {
    const long tot = (long)NI_P * NI_P;
    symscale_kernel<<<(tot + 255) / 256, 256, 0, stream>>>(adjIb, fI, NI, NI_P);
  }

  // ================= user graph =================
  mfma_gemm<1, 1, 0><<<47 * 48 / 2, 256, 0, stream>>>(
      Rh, Rl, Rh, Rl, Su, nullptr, NU, NU, NI_P, NI_P, NI_P, NU, 47, 47);
  {
    const int T = (NU + 31) / 32;  // 188
    mirror_kernel<<<T * (T - 1) / 2, 256, 0, stream>>>(Su, NU);
  }
  hipMemsetAsync(adjUb, 0, (long)NU_P * NU_P * sizeof(__bf16), stream);
  hipMemsetAsync(csU, 0, NU * sizeof(float), stream);
  topk_kernel<<<NU, 64, NU * sizeof(float), stream>>>(Su, invNu, adjUb, rsU,
                                                      csU, NU, NU_P, k_users_p);
  finalize_kernel<<<(NU + 255) / 256, 256, 0, stream>>>(rsU, csU, fU, NU);
  {
    const long tot = (long)NU_P * NU_P;
    symscale_kernel<<<(tot + 255) / 256, 256, 0, stream>>>(adjUb, fU, NU, NU_P);
  }

  // ================= propagation =================
  // prop1: Tt = T^T = adjI @ R^T  (bf16 out, full padded, on dead Rl region)
  mfma_gemm<0, 0, 1><<<32 * 47, 256, 0, stream>>>(
      adjIb, nullptr, Rh, nullptr, nullptr, Tt, NI_P, NU_P, NI_P, NI_P, NI_P,
      NU_P, 32, 47);
  // prop2: out = adjU @ T = adjUb @ Tt^T
  mfma_gemm<0, 0, 0><<<47 * 32, 256, 0, stream>>>(
      adjUb, nullptr, Tt, nullptr, out, nullptr, NU, NI, NU_P, NU_P, NU_P, NI,
      47, 32);
}

// Round 4
// 3830.580 us; speedup vs baseline: 5.2330x; 1.3645x over previous
//
#include <hip/hip_runtime.h>
#include <math.h>

#define EPS 1e-8f

constexpr int N_USERS = 6000;
constexpr int N_ITEMS = 4000;
constexpr int NU_P = 6016;  // 47 * 128
constexpr int NI_P = 4096;  // 32 * 128

typedef __bf16 bf16_8 __attribute__((ext_vector_type(8)));
typedef float f32_4 __attribute__((ext_vector_type(4)));

// ---------------------------------------------------------------------------
__device__ __forceinline__ void stage16(const __bf16* g, __bf16* l) {
  __builtin_amdgcn_global_load_lds(
      (const __attribute__((address_space(1))) void*)g,
      (__attribute__((address_space(3))) void*)l, 16, 0, 0);
}

// triangular decode: p -> (by, bx) with bx <= by
__device__ __forceinline__ void tri_decode(int p, int& by, int& bx) {
  int r = (int)((sqrtf(8.f * p + 1.f) - 1.f) * 0.5f);
  while ((r + 1) * (r + 2) / 2 <= p) r++;
  while (r * (r + 1) / 2 > p) r--;
  by = r;
  bx = p - r * (r + 1) / 2;
}

// grouped decode (G=8 rows, column-major within band) for L2 locality
__device__ __forceinline__ void grp_decode(int p, int nby, int nbx, int& by,
                                           int& bx) {
  const int G = 8;
  const int wide = G * nbx;
  const int band = p / wide;
  const int rem = p - band * wide;
  const int h = min(G, nby - band * G);
  by = band * G + rem % h;
  bx = rem / h;
}

// ---------------------------------------------------------------------------
// MFMA GEMM, 1D grid. C[M,N] = A @ B^T. A [M,K] bf16 k-contiguous (lda), B
// [N,K] (ldb), padded so any staged row is readable. SPLIT: 3-term bf16 hi/lo
// (~fp32). TRI: triangular grid decode (A==B symmetric gram, lower blocks).
// OUTBF16: store bf16 to Cb instead of fp32 to Cf.
// LDS k-slot swizzle applied via global source address at stage time;
// fragment reads land 2 lanes/bank (free, m136).
// ---------------------------------------------------------------------------
template <int SPLIT, int TRI, int OUTBF16>
__global__ __launch_bounds__(256) void mfma_gemm(
    const __bf16* __restrict__ Ah, const __bf16* __restrict__ Al,
    const __bf16* __restrict__ Bh, const __bf16* __restrict__ Bl,
    float* __restrict__ Cf, __bf16* __restrict__ Cb, int M, int N, int K,
    long lda, long ldb, long ldc, int nby, int nbx) {
  __shared__ __bf16 sAh[128 * 32];
  __shared__ __bf16 sBh[128 * 32];
  __shared__ __bf16 sAl[SPLIT ? 128 * 32 : 8];
  __shared__ __bf16 sBl[SPLIT ? 128 * 32 : 8];

  int by, bx;
  if (TRI)
    tri_decode(blockIdx.x, by, bx);
  else
    grp_decode(blockIdx.x, nby, nbx, by, bx);

  const int tid = threadIdx.x;
  const int lane = tid & 63;
  const int wave = tid >> 6;
  const int wm = (wave >> 1) * 64;
  const int wn = (wave & 1) * 64;
  const int lm = lane & 15;
  const int kg = lane >> 4;
  const long row0 = (long)by * 128;
  const long col0 = (long)bx * 128;

  f32_4 acc[4][4];
#pragma unroll
  for (int i = 0; i < 4; i++)
#pragma unroll
    for (int j = 0; j < 4; j++) acc[i][j] = (f32_4){0.f, 0.f, 0.f, 0.f};

  // staging: chunk c -> row c>>2, LDS offset c*16B; global kchunk swizzled
  const int c0 = tid, c1 = tid + 256;
  const int r0c = c0 >> 2, j0c = ((c0 & 3) - (r0c >> 1)) & 3;
  const int r1c = c1 >> 2, j1c = ((c1 & 3) - (r1c >> 1)) & 3;

  for (int k0 = 0; k0 < K; k0 += 32) {
    stage16(Ah + (row0 + r0c) * lda + k0 + j0c * 8, sAh + c0 * 8);
    stage16(Ah + (row0 + r1c) * lda + k0 + j1c * 8, sAh + c1 * 8);
    stage16(Bh + (col0 + r0c) * ldb + k0 + j0c * 8, sBh + c0 * 8);
    stage16(Bh + (col0 + r1c) * ldb + k0 + j1c * 8, sBh + c1 * 8);
    if (SPLIT) {
      stage16(Al + (row0 + r0c) * lda + k0 + j0c * 8, sAl + c0 * 8);
      stage16(Al + (row0 + r1c) * lda + k0 + j1c * 8, sAl + c1 * 8);
      stage16(Bl + (col0 + r0c) * ldb + k0 + j0c * 8, sBl + c0 * 8);
      stage16(Bl + (col0 + r1c) * ldb + k0 + j1c * 8, sBl + c1 * 8);
    }
    __syncthreads();

    bf16_8 ah[4], bh[4], alo[4], blo[4];
#pragma unroll
    for (int i = 0; i < 4; i++) {
      const int ra = wm + i * 16 + lm;
      const int rb = wn + i * 16 + lm;
      ah[i] = *(const bf16_8*)&sAh[(ra * 4 + ((kg + (ra >> 1)) & 3)) * 8];
      bh[i] = *(const bf16_8*)&sBh[(rb * 4 + ((kg + (rb >> 1)) & 3)) * 8];
      if (SPLIT) {
        alo[i] = *(const bf16_8*)&sAl[(ra * 4 + ((kg + (ra >> 1)) & 3)) * 8];
        blo[i] = *(const bf16_8*)&sBl[(rb * 4 + ((kg + (rb >> 1)) & 3)) * 8];
      }
    }
#pragma unroll
    for (int i = 0; i < 4; i++)
#pragma unroll
      for (int j = 0; j < 4; j++) {
        acc[i][j] = __builtin_amdgcn_mfma_f32_16x16x32_bf16(ah[i], bh[j],
                                                            acc[i][j], 0, 0, 0);
        if (SPLIT) {
          acc[i][j] = __builtin_amdgcn_mfma_f32_16x16x32_bf16(
              ah[i], blo[j], acc[i][j], 0, 0, 0);
          acc[i][j] = __builtin_amdgcn_mfma_f32_16x16x32_bf16(
              alo[i], bh[j], acc[i][j], 0, 0, 0);
        }
      }
    __syncthreads();
  }

  // epilogue: C/D layout col=lane&15, row=(lane>>4)*4+reg
#pragma unroll
  for (int i = 0; i < 4; i++)
#pragma unroll
    for (int j = 0; j < 4; j++)
#pragma unroll
      for (int r = 0; r < 4; r++) {
        const long gm = row0 + wm + i * 16 + kg * 4 + r;
        const long gn = col0 + wn + j * 16 + lm;
        if (gm < M && gn < N) {
          if (OUTBF16)
            Cb[gm * ldc + gn] = (__bf16)acc[i][j][r];
          else
            Cf[gm * ldc + gn] = acc[i][j][r];
        }
      }
}

// ---------------------------------------------------------------------------
// R [M,N] fp32 -> padded hi/lo bf16 [gridDim.y, Np]
// ---------------------------------------------------------------------------
__global__ __launch_bounds__(256) void pad_split_kernel(
    const float* __restrict__ R, __bf16* __restrict__ H, __bf16* __restrict__ L,
    int M, int N, int Np) {
  const int r = blockIdx.y;
  const int c = blockIdx.x * 256 + threadIdx.x;
  if (c >= Np) return;
  const float v = (r < M && c < N) ? R[(long)r * N + c] : 0.f;
  const __bf16 h = (__bf16)v;
  H[(long)r * Np + c] = h;
  L[(long)r * Np + c] = (__bf16)(v - (float)h);
}

// ---------------------------------------------------------------------------
// Transpose fp32 [M,N] -> padded bf16 [Np, Mp] hi/lo, LDS-tiled.
// ---------------------------------------------------------------------------
__global__ __launch_bounds__(256) void transpose_split_kernel(
    const float* __restrict__ R, __bf16* __restrict__ Th,
    __bf16* __restrict__ Tl, int M, int N, int Mp, int Np) {
  __shared__ float tile[32][33];
  const int tx = threadIdx.x & 31;
  const int ty = threadIdx.x >> 5;
  const int ri = blockIdx.y * 32;
  const int ci = blockIdx.x * 32;
#pragma unroll
  for (int k = 0; k < 4; k++) {
    const int r = ri + ty + k * 8, c = ci + tx;
    tile[ty + k * 8][tx] = (r < M && c < N) ? R[(long)r * N + c] : 0.f;
  }
  __syncthreads();
#pragma unroll
  for (int k = 0; k < 4; k++) {
    const int orow = ci + ty + k * 8;
    const int ocol = ri + tx;
    if (orow < Np && ocol < Mp) {
      const float v = tile[tx][ty + k * 8];
      Th[(long)orow * Mp + ocol] = (__bf16)v;
      if (Tl) Tl[(long)orow * Mp + ocol] = (__bf16)(v - (float)(__bf16)v);
    }
  }
}

// ---------------------------------------------------------------------------
// Mirror lower triangle of fp32 S [n,n] into strict upper, 32x32 tile pairs.
// ---------------------------------------------------------------------------
__global__ __launch_bounds__(256) void mirror_kernel(float* __restrict__ S,
                                                     int n) {
  __shared__ float tile[32][33];
  int by, bx;
  tri_decode(blockIdx.x, by, bx);
  const int tj = by + 1, ti = bx;  // tj > ti
  const int sr = tj * 32, sc = ti * 32;
  const int tx = threadIdx.x & 31;
  const int ty = threadIdx.x >> 5;
#pragma unroll
  for (int k = 0; k < 4; k++) {
    const int r = sr + ty + k * 8, c = sc + tx;
    tile[ty + k * 8][tx] = (r < n && c < n) ? S[(long)r * n + c] : 0.f;
  }
  __syncthreads();
#pragma unroll
  for (int k = 0; k < 4; k++) {
    const int r = sc + ty + k * 8, c = sr + tx;
    if (r < n && c < n) S[(long)r * n + c] = tile[tx][ty + k * 8];
  }
}

// ---------------------------------------------------------------------------
// norms
// ---------------------------------------------------------------------------
__global__ __launch_bounds__(256) void row_norm_inv(
    const float* __restrict__ R, float* __restrict__ inv_n, int M, int K) {
  __shared__ float red[256];
  const int row = blockIdx.x;
  float s = 0.f;
  for (int j = threadIdx.x; j < K; j += 256) {
    const float v = R[(long)row * K + j];
    s = fmaf(v, v, s);
  }
  red[threadIdx.x] = s;
  __syncthreads();
  for (int o = 128; o > 0; o >>= 1) {
    if (threadIdx.x < o) red[threadIdx.x] += red[threadIdx.x + o];
    __syncthreads();
  }
  if (threadIdx.x == 0) inv_n[row] = 1.f / (sqrtf(red[0]) + EPS);
}

// Column sums-of-squares, two-phase: grid (col_blocks, row_chunks). Each
// thread accumulates its column over a ~100-row chunk (coalesced), then one
// atomicAdd. acc must be pre-zeroed. Fixes the R3 0.7%-occupancy disaster.
__global__ __launch_bounds__(256) void col_sumsq_kernel(
    const float* __restrict__ R, float* __restrict__ acc, int M, int N,
    int rows_per_chunk) {
  const int j = blockIdx.x * 256 + threadIdx.x;
  if (j >= N) return;
  const int r0 = blockIdx.y * rows_per_chunk;
  const int r1 = min(M, r0 + rows_per_chunk);
  float s = 0.f;
  for (int i = r0; i < r1; i++) {
    const float v = R[(long)i * N + j];
    s = fmaf(v, v, s);
  }
  atomicAdd(&acc[j], s);
}

// inv_n[i] = 1/(sqrt(acc[i]) + EPS)
__global__ __launch_bounds__(256) void inv_norm_finalize(
    const float* __restrict__ acc, float* __restrict__ inv_n, int n) {
  const int i = blockIdx.x * 256 + threadIdx.x;
  if (i < n) inv_n[i] = 1.f / (sqrtf(acc[i]) + EPS);
}

// ---------------------------------------------------------------------------
// Top-k, one wave64 per row. Lane-private LDS slices, barrier-free selection
// loop, shfl-xor butterfly argmax (ties: min idx). bf16 adj + degree sums.
// ---------------------------------------------------------------------------
__global__ __launch_bounds__(64) void topk_kernel(
    const float* __restrict__ G, const float* __restrict__ inv_n,
    __bf16* __restrict__ adj, float* __restrict__ rowsum,
    float* __restrict__ colsum, int n, int np, const int* __restrict__ kptr) {
  extern __shared__ float rowv[];
  const int row = blockIdx.x;
  const int lane = threadIdx.x;
  const int k = *kptr;
  const float invr = inv_n[row];

  float lv = -INFINITY;
  int li = n;
  for (int j = lane; j < n; j += 64) {
    const float v = (j == row) ? -INFINITY : G[(long)row * n + j] * invr * inv_n[j];
    rowv[j] = v;
    if (v > lv) { lv = v; li = j; }
  }

  float rsum = 0.f;
  for (int t = 0; t < k; t++) {
    float v = lv;
    int i = li;
#pragma unroll
    for (int off = 32; off > 0; off >>= 1) {
      const float ov = __shfl_xor(v, off);
      const int oi = __shfl_xor(i, off);
      if (ov > v || (ov == v && oi < i)) { v = ov; i = oi; }
    }
    if (lane == 0) {
      adj[(long)row * np + i] = (__bf16)v;
      atomicAdd(&colsum[i], v);
      rsum += v;
    }
    if ((i & 63) == lane) {
      rowv[i] = -INFINITY;
      lv = -INFINITY;
      li = n;
      for (int j = lane; j < n; j += 64) {
        const float vv = rowv[j];
        if (vv > lv) { lv = vv; li = j; }
      }
    }
  }
  if (lane == 0) rowsum[row] = rsum;
}

// f[i] = 1/sqrt(0.5*(rowsum+colsum) + EPS)
__global__ __launch_bounds__(256) void finalize_kernel(
    const float* __restrict__ rs, const float* __restrict__ cs,
    float* __restrict__ f, int n) {
  const int i = blockIdx.x * 256 + threadIdx.x;
  if (i < n) f[i] = rsqrtf(0.5f * (rs[i] + cs[i]) + EPS);
}

// in-place: adj[i,j] = adj[j,i] = 0.5*(adj[i,j]+adj[j,i]) * f[i]*f[j]
__global__ __launch_bounds__(256) void symscale_kernel(
    __bf16* __restrict__ adj, const float* __restrict__ f, int n, int np) {
  const long idx = (long)blockIdx.x * 256 + threadIdx.x;
  if (idx >= (long)np * np) return;
  const int i = (int)(idx / np);
  const int j = (int)(idx % np);
  if (j <= i || i >= n || j >= n) return;
  const float a = (float)adj[(long)i * np + j];
  const float b = (float)adj[(long)j * np + i];
  const float m = 0.5f * (a + b) * f[i] * f[j];
  adj[(long)i * np + j] = (__bf16)m;
  adj[(long)j * np + i] = (__bf16)m;
}

// ---------------------------------------------------------------------------
extern "C" void kernel_launch(void* const* d_in, const int* in_sizes, int n_in,
                              void* d_out, int out_size, void* d_ws,
                              size_t ws_size, hipStream_t stream) {
  const float* R = (const float*)d_in[0];
  const int* k_users_p = (const int*)d_in[1];
  const int* k_items_p = (const int*)d_in[2];
  float* out = (float*)d_out;
  const int NU = N_USERS, NI = N_ITEMS;

  // ---- workspace (peak ~352 MB) ----
  char* ws = (char*)d_ws;
  float* invNu = (float*)(ws + 0);        // 24 KB
  float* invNi = (float*)(ws + 32768);    // 16 KB
  float* rsU = (float*)(ws + 65536);      // 24 KB
  float* csU = (float*)(ws + 98304);      // 24 KB
  float* rsI = (float*)(ws + 131072);     // 16 KB
  float* csI = (float*)(ws + 163840);     // 16 KB
  float* fU = (float*)(ws + 196608);      // 24 KB
  float* fI = (float*)(ws + 229376);      // 16 KB
  float* nrmI = (float*)(ws + 262144);    // 16 KB (col sumsq accumulator)
  const long MB = 1000000L;
  __bf16* Rh = (__bf16*)(ws + 1 * MB);     // [NU_P,NI_P] until prop1
  __bf16* Rl = (__bf16*)(ws + 51 * MB);    // [NU_P,NI_P] until user gram
  __bf16* Tt = (__bf16*)(ws + 51 * MB);    // [NI_P,NU_P] prop1->prop2 (on Rl)
  __bf16* RhT = (__bf16*)(ws + 101 * MB);  // [NI_P,NU_P] until item gram
  __bf16* RlT = (__bf16*)(ws + 151 * MB);  // [NI_P,NU_P] until item gram
  float* Si = (float*)(ws + 201 * MB);     // [4000^2] until item topk
  float* Su = (float*)(ws + 101 * MB);     // [6000^2] after RhT/RlT/Si dead
  __bf16* adjUb = (__bf16*)(ws + 245 * MB);  // [NU_P^2] until prop2
  __bf16* adjIb = (__bf16*)(ws + 318 * MB);  // [NI_P^2] until prop1

  // ---- norms + bf16 conversions ----
  row_norm_inv<<<NU, 256, 0, stream>>>(R, invNu, NU, NI);
  hipMemsetAsync(nrmI, 0, NI * sizeof(float), stream);
  col_sumsq_kernel<<<dim3((NI + 255) / 256, 60), 256, 0, stream>>>(R, nrmI, NU,
                                                                   NI, 100);
  inv_norm_finalize<<<(NI + 255) / 256, 256, 0, stream>>>(nrmI, invNi, NI);
  pad_split_kernel<<<dim3(NI_P / 256, NU_P), 256, 0, stream>>>(R, Rh, Rl, NU,
                                                               NI, NI_P);
  transpose_split_kernel<<<dim3(NI_P / 32, NU_P / 32), 256, 0, stream>>>(
      R, RhT, RlT, NU, NI, NU_P, NI_P);

  // ================= item graph =================
  mfma_gemm<1, 1, 0><<<32 * 33 / 2, 256, 0, stream>>>(
      RhT, RlT, RhT, RlT, Si, nullptr, NI, NI, NU_P, NU_P, NU_P, NI, 32, 32);
  {
    const int T = (NI + 31) / 32;  // 125
    mirror_kernel<<<T * (T - 1) / 2, 256, 0, stream>>>(Si, NI);
  }
  hipMemsetAsync(adjIb, 0, (long)NI_P * NI_P * sizeof(__bf16), stream);
  hipMemsetAsync(csI, 0, NI * sizeof(float), stream);
  topk_kernel<<<NI, 64, NI * sizeof(float), stream>>>(Si, invNi, adjIb, rsI,
                                                      csI, NI, NI_P, k_items_p);
  finalize_kernel<<<(NI + 255) / 256, 256, 0, stream>>>(rsI, csI, fI, NI);
  {
    const long tot = (long)NI_P * NI_P;
    symscale_kernel<<<(tot + 255) / 256, 256, 0, stream>>>(adjIb, fI, NI, NI_P);
  }

  // ================= user graph =================
  mfma_gemm<1, 1, 0><<<47 * 48 / 2, 256, 0, stream>>>(
      Rh, Rl, Rh, Rl, Su, nullptr, NU, NU, NI_P, NI_P, NI_P, NU, 47, 47);
  {
    const int T = (NU + 31) / 32;  // 188
    mirror_kernel<<<T * (T - 1) / 2, 256, 0, stream>>>(Su, NU);
  }
  hipMemsetAsync(adjUb, 0, (long)NU_P * NU_P * sizeof(__bf16), stream);
  hipMemsetAsync(csU, 0, NU * sizeof(float), stream);
  topk_kernel<<<NU, 64, NU * sizeof(float), stream>>>(Su, invNu, adjUb, rsU,
                                                      csU, NU, NU_P, k_users_p);
  finalize_kernel<<<(NU + 255) / 256, 256, 0, stream>>>(rsU, csU, fU, NU);
  {
    const long tot = (long)NU_P * NU_P;
    symscale_kernel<<<(tot + 255) / 256, 256, 0, stream>>>(adjUb, fU, NU, NU_P);
  }

  // ================= propagation =================
  // prop1: Tt = T^T = adjI @ R^T  (bf16 out, full padded, on dead Rl region)
  mfma_gemm<0, 0, 1><<<32 * 47, 256, 0, stream>>>(
      adjIb, nullptr, Rh, nullptr, nullptr, Tt, NI_P, NU_P, NI_P, NI_P, NI_P,
      NU_P, 32, 47);
  // prop2: out = adjU @ T = adjUb @ Tt^T
  mfma_gemm<0, 0, 0><<<47 * 32, 256, 0, stream>>>(
      adjUb, nullptr, Tt, nullptr, out, nullptr, NU, NI, NU_P, NU_P, NU_P, NI,
      47, 32);
}

// Round 5
// 2714.818 us; speedup vs baseline: 7.3837x; 1.4110x over previous
//
#include <hip/hip_runtime.h>
#include <math.h>

#define EPS 1e-8f

constexpr int N_USERS = 6000;
constexpr int N_ITEMS = 4000;
constexpr int NU_P = 6016;  // 47 * 128
constexpr int NI_P = 4096;  // 32 * 128

typedef __bf16 bf16_8 __attribute__((ext_vector_type(8)));
typedef float f32_4 __attribute__((ext_vector_type(4)));

// ---------------------------------------------------------------------------
__device__ __forceinline__ void stage16(const __bf16* g, __bf16* l) {
  __builtin_amdgcn_global_load_lds(
      (const __attribute__((address_space(1))) void*)g,
      (__attribute__((address_space(3))) void*)l, 16, 0, 0);
}

// triangular decode: p -> (by, bx) with bx <= by
__device__ __forceinline__ void tri_decode(int p, int& by, int& bx) {
  int r = (int)((sqrtf(8.f * p + 1.f) - 1.f) * 0.5f);
  while ((r + 1) * (r + 2) / 2 <= p) r++;
  while (r * (r + 1) / 2 > p) r--;
  by = r;
  bx = p - r * (r + 1) / 2;
}

// grouped decode (G=8 rows, column-major within band) for L2 locality
__device__ __forceinline__ void grp_decode(int p, int nby, int nbx, int& by,
                                           int& bx) {
  const int G = 8;
  const int wide = G * nbx;
  const int band = p / wide;
  const int rem = p - band * wide;
  const int h = min(G, nby - band * G);
  by = band * G + rem % h;
  bx = rem / h;
}

// ---------------------------------------------------------------------------
// MFMA GEMM, 1D grid. C[M,N] = A @ B^T. A [M,K] bf16 k-contiguous (lda), B
// [N,K] (ldb), padded so any staged row is readable. SPLIT: 3-term bf16 hi/lo
// (~fp32). TRI: triangular grid decode (A==B symmetric gram, lower blocks).
// OUTBF16: store bf16 to Cb instead of fp32 to Cf.
// LDS k-slot swizzle applied via global source address at stage time;
// fragment reads land 2 lanes/bank (free, m136).
// ---------------------------------------------------------------------------
template <int SPLIT, int TRI, int OUTBF16>
__global__ __launch_bounds__(256) void mfma_gemm(
    const __bf16* __restrict__ Ah, const __bf16* __restrict__ Al,
    const __bf16* __restrict__ Bh, const __bf16* __restrict__ Bl,
    float* __restrict__ Cf, __bf16* __restrict__ Cb, int M, int N, int K,
    long lda, long ldb, long ldc, int nby, int nbx) {
  __shared__ __bf16 sAh[128 * 32];
  __shared__ __bf16 sBh[128 * 32];
  __shared__ __bf16 sAl[SPLIT ? 128 * 32 : 8];
  __shared__ __bf16 sBl[SPLIT ? 128 * 32 : 8];

  int by, bx;
  if (TRI)
    tri_decode(blockIdx.x, by, bx);
  else
    grp_decode(blockIdx.x, nby, nbx, by, bx);

  const int tid = threadIdx.x;
  const int lane = tid & 63;
  const int wave = tid >> 6;
  const int wm = (wave >> 1) * 64;
  const int wn = (wave & 1) * 64;
  const int lm = lane & 15;
  const int kg = lane >> 4;
  const long row0 = (long)by * 128;
  const long col0 = (long)bx * 128;

  f32_4 acc[4][4];
#pragma unroll
  for (int i = 0; i < 4; i++)
#pragma unroll
    for (int j = 0; j < 4; j++) acc[i][j] = (f32_4){0.f, 0.f, 0.f, 0.f};

  // staging: chunk c -> row c>>2, LDS offset c*16B; global kchunk swizzled
  const int c0 = tid, c1 = tid + 256;
  const int r0c = c0 >> 2, j0c = ((c0 & 3) - (r0c >> 1)) & 3;
  const int r1c = c1 >> 2, j1c = ((c1 & 3) - (r1c >> 1)) & 3;

  for (int k0 = 0; k0 < K; k0 += 32) {
    stage16(Ah + (row0 + r0c) * lda + k0 + j0c * 8, sAh + c0 * 8);
    stage16(Ah + (row0 + r1c) * lda + k0 + j1c * 8, sAh + c1 * 8);
    stage16(Bh + (col0 + r0c) * ldb + k0 + j0c * 8, sBh + c0 * 8);
    stage16(Bh + (col0 + r1c) * ldb + k0 + j1c * 8, sBh + c1 * 8);
    if (SPLIT) {
      stage16(Al + (row0 + r0c) * lda + k0 + j0c * 8, sAl + c0 * 8);
      stage16(Al + (row0 + r1c) * lda + k0 + j1c * 8, sAl + c1 * 8);
      stage16(Bl + (col0 + r0c) * ldb + k0 + j0c * 8, sBl + c0 * 8);
      stage16(Bl + (col0 + r1c) * ldb + k0 + j1c * 8, sBl + c1 * 8);
    }
    __syncthreads();

    bf16_8 ah[4], bh[4], alo[4], blo[4];
#pragma unroll
    for (int i = 0; i < 4; i++) {
      const int ra = wm + i * 16 + lm;
      const int rb = wn + i * 16 + lm;
      ah[i] = *(const bf16_8*)&sAh[(ra * 4 + ((kg + (ra >> 1)) & 3)) * 8];
      bh[i] = *(const bf16_8*)&sBh[(rb * 4 + ((kg + (rb >> 1)) & 3)) * 8];
      if (SPLIT) {
        alo[i] = *(const bf16_8*)&sAl[(ra * 4 + ((kg + (ra >> 1)) & 3)) * 8];
        blo[i] = *(const bf16_8*)&sBl[(rb * 4 + ((kg + (rb >> 1)) & 3)) * 8];
      }
    }
#pragma unroll
    for (int i = 0; i < 4; i++)
#pragma unroll
      for (int j = 0; j < 4; j++) {
        acc[i][j] = __builtin_amdgcn_mfma_f32_16x16x32_bf16(ah[i], bh[j],
                                                            acc[i][j], 0, 0, 0);
        if (SPLIT) {
          acc[i][j] = __builtin_amdgcn_mfma_f32_16x16x32_bf16(
              ah[i], blo[j], acc[i][j], 0, 0, 0);
          acc[i][j] = __builtin_amdgcn_mfma_f32_16x16x32_bf16(
              alo[i], bh[j], acc[i][j], 0, 0, 0);
        }
      }
    __syncthreads();
  }

  // epilogue: C/D layout col=lane&15, row=(lane>>4)*4+reg
#pragma unroll
  for (int i = 0; i < 4; i++)
#pragma unroll
    for (int j = 0; j < 4; j++)
#pragma unroll
      for (int r = 0; r < 4; r++) {
        const long gm = row0 + wm + i * 16 + kg * 4 + r;
        const long gn = col0 + wn + j * 16 + lm;
        if (gm < M && gn < N) {
          if (OUTBF16)
            Cb[gm * ldc + gn] = (__bf16)acc[i][j][r];
          else
            Cf[gm * ldc + gn] = acc[i][j][r];
        }
      }
}

// ---------------------------------------------------------------------------
// R [M,N] fp32 -> padded hi/lo bf16 [gridDim.y, Np]
// ---------------------------------------------------------------------------
__global__ __launch_bounds__(256) void pad_split_kernel(
    const float* __restrict__ R, __bf16* __restrict__ H, __bf16* __restrict__ L,
    int M, int N, int Np) {
  const int r = blockIdx.y;
  const int c = blockIdx.x * 256 + threadIdx.x;
  if (c >= Np) return;
  const float v = (r < M && c < N) ? R[(long)r * N + c] : 0.f;
  const __bf16 h = (__bf16)v;
  H[(long)r * Np + c] = h;
  L[(long)r * Np + c] = (__bf16)(v - (float)h);
}

// ---------------------------------------------------------------------------
// Transpose fp32 [M,N] -> padded bf16 [Np, Mp] hi/lo, LDS-tiled.
// ---------------------------------------------------------------------------
__global__ __launch_bounds__(256) void transpose_split_kernel(
    const float* __restrict__ R, __bf16* __restrict__ Th,
    __bf16* __restrict__ Tl, int M, int N, int Mp, int Np) {
  __shared__ float tile[32][33];
  const int tx = threadIdx.x & 31;
  const int ty = threadIdx.x >> 5;
  const int ri = blockIdx.y * 32;
  const int ci = blockIdx.x * 32;
#pragma unroll
  for (int k = 0; k < 4; k++) {
    const int r = ri + ty + k * 8, c = ci + tx;
    tile[ty + k * 8][tx] = (r < M && c < N) ? R[(long)r * N + c] : 0.f;
  }
  __syncthreads();
#pragma unroll
  for (int k = 0; k < 4; k++) {
    const int orow = ci + ty + k * 8;
    const int ocol = ri + tx;
    if (orow < Np && ocol < Mp) {
      const float v = tile[tx][ty + k * 8];
      Th[(long)orow * Mp + ocol] = (__bf16)v;
      if (Tl) Tl[(long)orow * Mp + ocol] = (__bf16)(v - (float)(__bf16)v);
    }
  }
}

// ---------------------------------------------------------------------------
// Mirror lower triangle of fp32 S [n,n] into strict upper, 32x32 tile pairs.
// ---------------------------------------------------------------------------
__global__ __launch_bounds__(256) void mirror_kernel(float* __restrict__ S,
                                                     int n) {
  __shared__ float tile[32][33];
  int by, bx;
  tri_decode(blockIdx.x, by, bx);
  const int tj = by + 1, ti = bx;  // tj > ti
  const int sr = tj * 32, sc = ti * 32;
  const int tx = threadIdx.x & 31;
  const int ty = threadIdx.x >> 5;
#pragma unroll
  for (int k = 0; k < 4; k++) {
    const int r = sr + ty + k * 8, c = sc + tx;
    tile[ty + k * 8][tx] = (r < n && c < n) ? S[(long)r * n + c] : 0.f;
  }
  __syncthreads();
#pragma unroll
  for (int k = 0; k < 4; k++) {
    const int r = sc + ty + k * 8, c = sr + tx;
    if (r < n && c < n) S[(long)r * n + c] = tile[tx][ty + k * 8];
  }
}

// ---------------------------------------------------------------------------
// norms
// ---------------------------------------------------------------------------
__global__ __launch_bounds__(256) void row_norm_inv(
    const float* __restrict__ R, float* __restrict__ inv_n, int M, int K) {
  __shared__ float red[256];
  const int row = blockIdx.x;
  float s = 0.f;
  for (int j = threadIdx.x; j < K; j += 256) {
    const float v = R[(long)row * K + j];
    s = fmaf(v, v, s);
  }
  red[threadIdx.x] = s;
  __syncthreads();
  for (int o = 128; o > 0; o >>= 1) {
    if (threadIdx.x < o) red[threadIdx.x] += red[threadIdx.x + o];
    __syncthreads();
  }
  if (threadIdx.x == 0) inv_n[row] = 1.f / (sqrtf(red[0]) + EPS);
}

// Column sums-of-squares, two-phase (coalesced, high occupancy).
__global__ __launch_bounds__(256) void col_sumsq_kernel(
    const float* __restrict__ R, float* __restrict__ acc, int M, int N,
    int rows_per_chunk) {
  const int j = blockIdx.x * 256 + threadIdx.x;
  if (j >= N) return;
  const int r0 = blockIdx.y * rows_per_chunk;
  const int r1 = min(M, r0 + rows_per_chunk);
  float s = 0.f;
  for (int i = r0; i < r1; i++) {
    const float v = R[(long)i * N + j];
    s = fmaf(v, v, s);
  }
  atomicAdd(&acc[j], s);
}

// inv_n[i] = 1/(sqrt(acc[i]) + EPS)
__global__ __launch_bounds__(256) void inv_norm_finalize(
    const float* __restrict__ acc, float* __restrict__ inv_n, int n) {
  const int i = blockIdx.x * 256 + threadIdx.x;
  if (i < n) inv_n[i] = 1.f / (sqrtf(acc[i]) + EPS);
}

// ---------------------------------------------------------------------------
// Top-k, one wave64 per row. Each lane keeps a sorted top-4 (val,idx) register
// list over its private slice (j % 64 == lane); extraction = butterfly argmax
// over lane heads + register pop. LDS slice (removed marked -inf) is only
// rescanned when a lane's list empties (expected <1 rescan/row). Barrier-free.
// Tie-break: strict-greater insertion + (==, min idx) butterfly matches
// jax.lax.top_k stability. Writes bf16 adj (pre-zeroed), rowsum, atomic colsum.
// ---------------------------------------------------------------------------
__global__ __launch_bounds__(64) void topk_kernel(
    const float* __restrict__ G, const float* __restrict__ inv_n,
    __bf16* __restrict__ adj, float* __restrict__ rowsum,
    float* __restrict__ colsum, int n, int np, const int* __restrict__ kptr) {
  extern __shared__ float rowv[];
  const int row = blockIdx.x;
  const int lane = threadIdx.x;
  const int k = *kptr;
  const float invr = inv_n[row];

  float v0 = -INFINITY, v1 = -INFINITY, v2 = -INFINITY, v3 = -INFINITY;
  int i0 = n, i1 = n, i2 = n, i3 = n;

  for (int j = lane; j < n; j += 64) {
    const float v =
        (j == row) ? -INFINITY : G[(long)row * n + j] * invr * inv_n[j];
    rowv[j] = v;
    if (v > v3) {
      if (v > v1) {
        if (v > v0) {
          v3 = v2; i3 = i2; v2 = v1; i2 = i1; v1 = v0; i1 = i0; v0 = v; i0 = j;
        } else {
          v3 = v2; i3 = i2; v2 = v1; i2 = i1; v1 = v; i1 = j;
        }
      } else {
        if (v > v2) {
          v3 = v2; i3 = i2; v2 = v; i2 = j;
        } else {
          v3 = v; i3 = j;
        }
      }
    }
  }

  float rsum = 0.f;
  for (int t = 0; t < k; t++) {
    float v = v0;
    int i = i0;
#pragma unroll
    for (int off = 32; off > 0; off >>= 1) {
      const float ov = __shfl_xor(v, off);
      const int oi = __shfl_xor(i, off);
      if (ov > v || (ov == v && oi < i)) { v = ov; i = oi; }
    }
    if (lane == 0) {
      adj[(long)row * np + i] = (__bf16)v;
      atomicAdd(&colsum[i], v);
      rsum += v;
    }
    if ((i & 63) == lane) {
      rowv[i] = -INFINITY;  // mark removed (my slice; no cross-lane access)
      v0 = v1; i0 = i1; v1 = v2; i1 = i2; v2 = v3; i2 = i3;
      v3 = -INFINITY; i3 = n;
      if (i0 == n) {  // list exhausted -> rare rescan of my slice
        for (int j = lane; j < n; j += 64) {
          const float vv = rowv[j];
          if (vv > v3) {
            if (vv > v1) {
              if (vv > v0) {
                v3 = v2; i3 = i2; v2 = v1; i2 = i1; v1 = v0; i1 = i0;
                v0 = vv; i0 = j;
              } else {
                v3 = v2; i3 = i2; v2 = v1; i2 = i1; v1 = vv; i1 = j;
              }
            } else {
              if (vv > v2) {
                v3 = v2; i3 = i2; v2 = vv; i2 = j;
              } else {
                v3 = vv; i3 = j;
              }
            }
          }
        }
      }
    }
  }
  if (lane == 0) rowsum[row] = rsum;
}

// f[i] = 1/sqrt(0.5*(rowsum+colsum) + EPS)
__global__ __launch_bounds__(256) void finalize_kernel(
    const float* __restrict__ rs, const float* __restrict__ cs,
    float* __restrict__ f, int n) {
  const int i = blockIdx.x * 256 + threadIdx.x;
  if (i < n) f[i] = rsqrtf(0.5f * (rs[i] + cs[i]) + EPS);
}

// in-place: adj[i,j] = adj[j,i] = 0.5*(adj[i,j]+adj[j,i]) * f[i]*f[j]
__global__ __launch_bounds__(256) void symscale_kernel(
    __bf16* __restrict__ adj, const float* __restrict__ f, int n, int np) {
  const long idx = (long)blockIdx.x * 256 + threadIdx.x;
  if (idx >= (long)np * np) return;
  const int i = (int)(idx / np);
  const int j = (int)(idx % np);
  if (j <= i || i >= n || j >= n) return;
  const float a = (float)adj[(long)i * np + j];
  const float b = (float)adj[(long)j * np + i];
  const float m = 0.5f * (a + b) * f[i] * f[j];
  adj[(long)i * np + j] = (__bf16)m;
  adj[(long)j * np + i] = (__bf16)m;
}

// ---------------------------------------------------------------------------
extern "C" void kernel_launch(void* const* d_in, const int* in_sizes, int n_in,
                              void* d_out, int out_size, void* d_ws,
                              size_t ws_size, hipStream_t stream) {
  const float* R = (const float*)d_in[0];
  const int* k_users_p = (const int*)d_in[1];
  const int* k_items_p = (const int*)d_in[2];
  float* out = (float*)d_out;
  const int NU = N_USERS, NI = N_ITEMS;

  // ---- workspace (peak ~352 MB) ----
  char* ws = (char*)d_ws;
  float* invNu = (float*)(ws + 0);        // 24 KB
  float* invNi = (float*)(ws + 32768);    // 16 KB
  float* rsU = (float*)(ws + 65536);      // 24 KB
  float* csU = (float*)(ws + 98304);      // 24 KB
  float* rsI = (float*)(ws + 131072);     // 16 KB
  float* csI = (float*)(ws + 163840);     // 16 KB
  float* fU = (float*)(ws + 196608);      // 24 KB
  float* fI = (float*)(ws + 229376);      // 16 KB
  float* nrmI = (float*)(ws + 262144);    // 16 KB (col sumsq accumulator)
  const long MB = 1000000L;
  __bf16* Rh = (__bf16*)(ws + 1 * MB);     // [NU_P,NI_P] until prop1
  __bf16* Rl = (__bf16*)(ws + 51 * MB);    // [NU_P,NI_P] until user gram
  __bf16* Tt = (__bf16*)(ws + 51 * MB);    // [NI_P,NU_P] prop1->prop2 (on Rl)
  __bf16* RhT = (__bf16*)(ws + 101 * MB);  // [NI_P,NU_P] until item gram
  __bf16* RlT = (__bf16*)(ws + 151 * MB);  // [NI_P,NU_P] until item gram
  float* Si = (float*)(ws + 201 * MB);     // [4000^2] until item topk
  float* Su = (float*)(ws + 101 * MB);     // [6000^2] after RhT/RlT/Si dead
  __bf16* adjUb = (__bf16*)(ws + 245 * MB);  // [NU_P^2] until prop2
  __bf16* adjIb = (__bf16*)(ws + 318 * MB);  // [NI_P^2] until prop1

  // ---- norms + bf16 conversions ----
  row_norm_inv<<<NU, 256, 0, stream>>>(R, invNu, NU, NI);
  hipMemsetAsync(nrmI, 0, NI * sizeof(float), stream);
  col_sumsq_kernel<<<dim3((NI + 255) / 256, 60), 256, 0, stream>>>(R, nrmI, NU,
                                                                   NI, 100);
  inv_norm_finalize<<<(NI + 255) / 256, 256, 0, stream>>>(nrmI, invNi, NI);
  pad_split_kernel<<<dim3(NI_P / 256, NU_P), 256, 0, stream>>>(R, Rh, Rl, NU,
                                                               NI, NI_P);
  transpose_split_kernel<<<dim3(NI_P / 32, NU_P / 32), 256, 0, stream>>>(
      R, RhT, RlT, NU, NI, NU_P, NI_P);

  // ================= item graph =================
  mfma_gemm<1, 1, 0><<<32 * 33 / 2, 256, 0, stream>>>(
      RhT, RlT, RhT, RlT, Si, nullptr, NI, NI, NU_P, NU_P, NU_P, NI, 32, 32);
  {
    const int T = (NI + 31) / 32;  // 125
    mirror_kernel<<<T * (T - 1) / 2, 256, 0, stream>>>(Si, NI);
  }
  hipMemsetAsync(adjIb, 0, (long)NI_P * NI_P * sizeof(__bf16), stream);
  hipMemsetAsync(csI, 0, NI * sizeof(float), stream);
  topk_kernel<<<NI, 64, NI * sizeof(float), stream>>>(Si, invNi, adjIb, rsI,
                                                      csI, NI, NI_P, k_items_p);
  finalize_kernel<<<(NI + 255) / 256, 256, 0, stream>>>(rsI, csI, fI, NI);
  {
    const long tot = (long)NI_P * NI_P;
    symscale_kernel<<<(tot + 255) / 256, 256, 0, stream>>>(adjIb, fI, NI, NI_P);
  }

  // ================= user graph =================
  mfma_gemm<1, 1, 0><<<47 * 48 / 2, 256, 0, stream>>>(
      Rh, Rl, Rh, Rl, Su, nullptr, NU, NU, NI_P, NI_P, NI_P, NU, 47, 47);
  {
    const int T = (NU + 31) / 32;  // 188
    mirror_kernel<<<T * (T - 1) / 2, 256, 0, stream>>>(Su, NU);
  }
  hipMemsetAsync(adjUb, 0, (long)NU_P * NU_P * sizeof(__bf16), stream);
  hipMemsetAsync(csU, 0, NU * sizeof(float), stream);
  topk_kernel<<<NU, 64, NU * sizeof(float), stream>>>(Su, invNu, adjUb, rsU,
                                                      csU, NU, NU_P, k_users_p);
  finalize_kernel<<<(NU + 255) / 256, 256, 0, stream>>>(rsU, csU, fU, NU);
  {
    const long tot = (long)NU_P * NU_P;
    symscale_kernel<<<(tot + 255) / 256, 256, 0, stream>>>(adjUb, fU, NU, NU_P);
  }

  // ================= propagation =================
  // prop1: Tt = T^T = adjI @ R^T  (bf16 out, full padded, on dead Rl region)
  mfma_gemm<0, 0, 1><<<32 * 47, 256, 0, stream>>>(
      adjIb, nullptr, Rh, nullptr, nullptr, Tt, NI_P, NU_P, NI_P, NI_P, NI_P,
      NU_P, 32, 47);
  // prop2: out = adjU @ T = adjUb @ Tt^T
  mfma_gemm<0, 0, 0><<<47 * 32, 256, 0, stream>>>(
      adjUb, nullptr, Tt, nullptr, out, nullptr, NU, NI, NU_P, NU_P, NU_P, NI,
      47, 32);
}